// Round 1
// baseline (255.123 us; speedup 1.0000x reference)
//
#include <hip/hip_runtime.h>
#include <math.h>

// MoELoRA dims (fixed by the problem)
#define NTOK   16384      // B*S
#define DDIM   1024
#define NE     8
#define NG     2
#define NR     8
#define ODIM   1024
#define NOUT   3072
#define NF     128        // E*G*R down-proj features
#define FP     144        // padded GEMM1 cols: 128 h + 8 logits + 8 zero
#define SCALE  2.0f

// ws layout (floats)
#define WS_AT   0                       // At  [1024][144]   = 147456
#define WS_BWT  147456                  // BwT [2][64][1024] = 131072
#define WS_WH   (147456 + 131072)       // wh  [16384][128]  = 2097152

// ---------------------------------------------------------------------------
// Kernel 0a: build At[d][f] = concat(A, W_route)^T, padded to 144 cols
__global__ __launch_bounds__(256) void k0_at(const float* __restrict__ A,
                                             const float* __restrict__ Wr,
                                             float* __restrict__ At) {
    int idx = blockIdx.x * 256 + threadIdx.x;
    if (idx >= DDIM * FP) return;
    int d = idx / FP, f = idx % FP;
    float v = 0.0f;
    if (f < NF)            v = A[(size_t)f * DDIM + d];
    else if (f < NF + NE)  v = Wr[(size_t)(f - NF) * DDIM + d];
    At[idx] = v;
}

// Kernel 0b: BwT[g][er][o] = Bw[e][g][o][r], er = e*8+r
__global__ __launch_bounds__(256) void k0_bwt(const float* __restrict__ Bw,
                                              float* __restrict__ BwT) {
    int idx = blockIdx.x * 256 + threadIdx.x;
    if (idx >= NG * 64 * ODIM) return;
    int o  = idx & (ODIM - 1);
    int er = (idx >> 10) & 63;
    int g  = idx >> 16;
    int e = er >> 3, r = er & 7;
    BwT[idx] = Bw[((size_t)((e * NG + g) * ODIM + o)) * NR + r];
}

// ---------------------------------------------------------------------------
// Kernel 1: per 64-token tile: GEMM1 (X * At -> h[64][136]) + softmax over E
//           + route-weighting (*SCALE) -> wh[tok][128] in ws
__global__ __launch_bounds__(256) void k1_down(const float* __restrict__ x,
                                               const float* __restrict__ At,
                                               float* __restrict__ wh) {
    __shared__ float xst[16][68];     // [kk][tok], stride 68 (16B-aligned rows)
    __shared__ float wt[16][FP];      // [kk][f]
    __shared__ float hsm[64][137];    // [tok][f] h + logits/route

    const int t    = threadIdx.x;
    const int tokb = blockIdx.x * 64;
    const int tgrp = t >> 4;          // 0..15 -> 4 tokens each
    const int fgrp = t & 15;          // 0..15 -> features fgrp + 16*j

    float acc[4][9];
#pragma unroll
    for (int i = 0; i < 4; ++i)
#pragma unroll
        for (int j = 0; j < 9; ++j) acc[i][j] = 0.0f;

    const int ltok = t >> 2;          // x-staging: token 0..63
    const int lc4  = t & 3;           // float4 index within 16-wide k chunk

    for (int k0 = 0; k0 < DDIM; k0 += 16) {
        __syncthreads();
        // stage x[64][16] transposed -> xst[kk][tok]
        {
            float4 v = *(const float4*)(x + (size_t)(tokb + ltok) * DDIM + k0 + lc4 * 4);
            xst[lc4 * 4 + 0][ltok] = v.x;
            xst[lc4 * 4 + 1][ltok] = v.y;
            xst[lc4 * 4 + 2][ltok] = v.z;
            xst[lc4 * 4 + 3][ltok] = v.w;
        }
        // stage At[16][144] (already transposed in ws, contiguous float4)
        for (int idx = t; idx < 16 * (FP / 4); idx += 256) {   // 576 float4
            int kr = idx / (FP / 4), c4 = idx % (FP / 4);
            *(float4*)&wt[kr][c4 * 4] =
                *(const float4*)(At + (size_t)(k0 + kr) * FP + c4 * 4);
        }
        __syncthreads();

#pragma unroll 4
        for (int kk = 0; kk < 16; ++kk) {
            float4 xq = *(const float4*)&xst[kk][tgrp * 4];
            float xa[4] = {xq.x, xq.y, xq.z, xq.w};
#pragma unroll
            for (int j = 0; j < 9; ++j) {
                float wv = wt[kk][fgrp + 16 * j];
                acc[0][j] = fmaf(xa[0], wv, acc[0][j]);
                acc[1][j] = fmaf(xa[1], wv, acc[1][j]);
                acc[2][j] = fmaf(xa[2], wv, acc[2][j]);
                acc[3][j] = fmaf(xa[3], wv, acc[3][j]);
            }
        }
    }

    __syncthreads();
    // write h + logits to LDS (f = fgrp + 16*j; f<136 are real)
#pragma unroll
    for (int j = 0; j < 9; ++j) {
        int f = fgrp + 16 * j;
        if (f < NF + NE) {
#pragma unroll
            for (int i = 0; i < 4; ++i) hsm[tgrp * 4 + i][f] = acc[i][j];
        }
    }
    __syncthreads();

    // softmax over experts; fold SCALE into route
    if (t < 64) {
        float m = -1e30f;
#pragma unroll
        for (int e = 0; e < NE; ++e) m = fmaxf(m, hsm[t][NF + e]);
        float p[NE], s = 0.0f;
#pragma unroll
        for (int e = 0; e < NE; ++e) { p[e] = expf(hsm[t][NF + e] - m); s += p[e]; }
        float inv = SCALE / s;
#pragma unroll
        for (int e = 0; e < NE; ++e) hsm[t][NF + e] = p[e] * inv;
    }
    __syncthreads();

    // weight h by route (f>>4 == expert index)
    {
        int tok = t & 63, j0 = (t >> 6) * 32;
#pragma unroll
        for (int j = 0; j < 32; ++j) {
            int f = j0 + j;
            hsm[tok][f] *= hsm[tok][NF + (f >> 4)];
        }
    }
    __syncthreads();

    // write wh[tok][128] coalesced
    for (int idx = t; idx < 64 * NF; idx += 256) {
        int tok = idx >> 7, f = idx & 127;
        wh[(size_t)(tokb + tok) * NF + f] = hsm[tok][f];
    }
}

// ---------------------------------------------------------------------------
// Kernel 2: per (otile, 64-token tile): GEMM2 (wh_g[64][64] * BwT_g[64][128])
//           -> out cols, or zero-fill for the disabled middle third.
// grid.x = 24 o-tiles of 128 cols: 0..7 -> group0 (cols 0..1023),
// 8..15 -> zeros (cols 1024..2047), 16..23 -> group1 (cols 2048..3071)
__global__ __launch_bounds__(256) void k2_up(const float* __restrict__ wh,
                                             const float* __restrict__ BwT,
                                             float* __restrict__ out) {
    const int otile = blockIdx.x;
    const int tokb  = blockIdx.y * 64;
    const int t     = threadIdx.x;

    if (otile >= 8 && otile < 16) {
        int o0 = 1024 + (otile - 8) * 128;
        float4 z = {0.0f, 0.0f, 0.0f, 0.0f};
        for (int idx = t; idx < 64 * 32; idx += 256) {
            int tok = idx >> 5, c4 = idx & 31;
            *(float4*)(out + (size_t)(tokb + tok) * NOUT + o0 + c4 * 4) = z;
        }
        return;
    }

    const int g     = (otile < 8) ? 0 : 1;
    const int obase = (otile & 7) * 128;          // within group
    const int colb  = (g ? 2048 : 0) + obase;     // output column base

    __shared__ float whs[64][68];                 // [er][tok]
    __shared__ float bws[64][128];                // [er][c]

    // stage wh for this group, transposed -> whs[er][tok]
    for (int idx = t; idx < 64 * 16; idx += 256) {
        int tok = idx >> 4, er4 = idx & 15;
        int e = er4 >> 1, r0 = (er4 & 1) * 4;
        float4 v = *(const float4*)(wh + (size_t)(tokb + tok) * NF + e * 16 + g * 8 + r0);
        int er = er4 * 4;
        whs[er + 0][tok] = v.x;
        whs[er + 1][tok] = v.y;
        whs[er + 2][tok] = v.z;
        whs[er + 3][tok] = v.w;
    }
    // stage BwT tile [64][128]
    for (int idx = t; idx < 64 * 32; idx += 256) {
        int kk = idx >> 5, c4 = idx & 31;
        *(float4*)&bws[kk][c4 * 4] =
            *(const float4*)(BwT + (size_t)g * 65536 + (size_t)kk * ODIM + obase + c4 * 4);
    }
    __syncthreads();

    const int tgrp = t >> 4;   // 4 tokens
    const int ogrp = t & 15;   // 8 contiguous out cols
    float acc[4][8];
#pragma unroll
    for (int i = 0; i < 4; ++i)
#pragma unroll
        for (int j = 0; j < 8; ++j) acc[i][j] = 0.0f;

#pragma unroll 4
    for (int kk = 0; kk < 64; ++kk) {
        float4 xq = *(const float4*)&whs[kk][tgrp * 4];
        float xa[4] = {xq.x, xq.y, xq.z, xq.w};
        float4 w0 = *(const float4*)&bws[kk][ogrp * 8];
        float4 w1 = *(const float4*)&bws[kk][ogrp * 8 + 4];
        float wb[8] = {w0.x, w0.y, w0.z, w0.w, w1.x, w1.y, w1.z, w1.w};
#pragma unroll
        for (int i = 0; i < 4; ++i)
#pragma unroll
            for (int j = 0; j < 8; ++j)
                acc[i][j] = fmaf(xa[i], wb[j], acc[i][j]);
    }

    // epilogue: coalesced float4 stores into scattered columns
#pragma unroll
    for (int i = 0; i < 4; ++i) {
        float4 s0 = {acc[i][0], acc[i][1], acc[i][2], acc[i][3]};
        float4 s1 = {acc[i][4], acc[i][5], acc[i][6], acc[i][7]};
        float* p = out + (size_t)(tokb + tgrp * 4 + i) * NOUT + colb + ogrp * 8;
        *(float4*)(p + 0) = s0;
        *(float4*)(p + 4) = s1;
    }
}

// ---------------------------------------------------------------------------
extern "C" void kernel_launch(void* const* d_in, const int* in_sizes, int n_in,
                              void* d_out, int out_size, void* d_ws, size_t ws_size,
                              hipStream_t stream) {
    const float* x  = (const float*)d_in[0];
    const float* Wr = (const float*)d_in[1];
    const float* A  = (const float*)d_in[2];
    const float* Bw = (const float*)d_in[3];
    float* ws  = (float*)d_ws;
    float* At  = ws + WS_AT;
    float* BwT = ws + WS_BWT;
    float* wh  = ws + WS_WH;
    float* out = (float*)d_out;

    k0_at <<<(DDIM * FP + 255) / 256, 256, 0, stream>>>(A, Wr, At);
    k0_bwt<<<(NG * 64 * ODIM + 255) / 256, 256, 0, stream>>>(Bw, BwT);
    k1_down<<<NTOK / 64, 256, 0, stream>>>(x, At, wh);
    k2_up<<<dim3(24, NTOK / 64), 256, 0, stream>>>(wh, BwT, out);
}

// Round 2
// 103.648 us; speedup vs baseline: 2.4614x; 2.4614x over previous
//
#include <hip/hip_runtime.h>
#include <math.h>

// MoELoRA dims (fixed by the problem)
#define NTOK   16384      // B*S
#define DDIM   1024
#define NE     8
#define NF     128        // E*G*R down-proj features (f = e*16 + g*8 + r)
#define FP     144        // GEMM1 N: 128 h + 8 logits + 8 zero  (9 MFMA N-tiles)
#define ODIM   1024
#define NOUT   3072
#define SCALE  2.0f

typedef __attribute__((ext_vector_type(8))) short bf16x8;
typedef __attribute__((ext_vector_type(4))) float f32x4;

// ws layout (bytes)
#define WS_ABT 0                        // bf16 [144][1024]   = 294912 B
#define WS_BBT 294912                   // bf16 [2][1024][64] = 262144 B
#define WS_WH  557056                   // bf16 [16384][128]  = 4 MiB

// pack two fp32 -> (bf16(a) | bf16(b)<<16), round-to-nearest-even
__device__ inline unsigned f2bf(float a, float b) {
    union { float f; unsigned u; } ua, ub;
    ua.f = a; ub.f = b;
    unsigned x = ua.u + (0x7fffu + ((ua.u >> 16) & 1));
    unsigned y = ub.u + (0x7fffu + ((ub.u >> 16) & 1));
    return (x >> 16) | (y & 0xffff0000u);
}

// ---------------------------------------------------------------------------
// Prep: Abt[f][d] = bf16(concat(A, W_route, 0))   (A is already f-major)
//       Bbt[g][o][er] = bf16(Bw[e][g][o][r]), er = e*8+r
__global__ __launch_bounds__(256) void k_prep(const float* __restrict__ A,
                                              const float* __restrict__ Wr,
                                              const float* __restrict__ Bw,
                                              unsigned short* __restrict__ Abt,
                                              unsigned short* __restrict__ Bbt) {
    const int b = blockIdx.x, t = threadIdx.x;
    if (b < FP) {
        const int col = t * 4;
        float4 v = {0.f, 0.f, 0.f, 0.f};
        if (b < NF)           v = *(const float4*)(A + (size_t)b * DDIM + col);
        else if (b < NF + NE) v = *(const float4*)(Wr + (size_t)(b - NF) * DDIM + col);
        uint2 p; p.x = f2bf(v.x, v.y); p.y = f2bf(v.z, v.w);
        *(uint2*)(Abt + (size_t)b * DDIM + col) = p;
    } else {
        const int idx = (b - FP) * 1024 + t * 4;      // over [2][1024][64]
        const int g = idx >> 16, o = (idx >> 6) & 1023, er = idx & 63;
        const int e = er >> 3, r0 = er & 7;           // r0 in {0,4}
        float4 v = *(const float4*)(Bw + ((size_t)(e * 2 + g) * ODIM + o) * 8 + r0);
        uint2 p; p.x = f2bf(v.x, v.y); p.y = f2bf(v.z, v.w);
        *(uint2*)(Bbt + idx) = p;
    }
}

// ---------------------------------------------------------------------------
// K1: per 64-token tile: MFMA GEMM (x_bf16[64][1024] * Abt^T -> h[64][144],
//     tile 8 = routing logits) + softmax + route-weight -> wh bf16 in ws.
// LDS: double-buffered x[64][72]bf16 + Abt-tile[144][72]bf16; epilogue
// aliases an fp32 hsm[64][148] over the same memory.
__global__ __launch_bounds__(256) void k1_down(const float* __restrict__ x,
                                               const unsigned short* __restrict__ Abt,
                                               unsigned short* __restrict__ wh) {
    __shared__ __align__(16) char smem[59904];
    short* xs  = (short*)smem;            // [2][64][72]
    short* as_ = (short*)(smem + 18432);  // [2][144][72]
    float* hsm = (float*)smem;            // [64][148] (alias, used after loop)

    const int t    = threadIdx.x;
    const int tokb = blockIdx.x * 64;
    const int lane = t & 63, w = t >> 6;
    const int l15  = lane & 15, lq = lane >> 4;

    f32x4 acc[9];
#pragma unroll
    for (int n = 0; n < 9; ++n) acc[n] = (f32x4){0.f, 0.f, 0.f, 0.f};

    float4 xr[4];
    uint4  ar[5];

    auto LD = [&](int k0) {   // issue global loads into regs (no LDS writes)
#pragma unroll
        for (int i = 0; i < 4; ++i) {
            int c = t + i * 256, tok = c >> 4, kq = c & 15;
            xr[i] = *(const float4*)(x + (size_t)(tokb + tok) * DDIM + k0 + kq * 4);
        }
#pragma unroll
        for (int i = 0; i < 5; ++i) {
            int c = t + i * 256;
            if (c < 1152) {
                int row = c >> 3, c8 = c & 7;
                ar[i] = *(const uint4*)(Abt + (size_t)row * DDIM + k0 + c8 * 8);
            }
        }
    };
    auto WR = [&](int buf) {  // cvt + LDS writes
        short* xb = xs + buf * (64 * 72);
        short* ab = as_ + buf * (144 * 72);
#pragma unroll
        for (int i = 0; i < 4; ++i) {
            int c = t + i * 256, tok = c >> 4, kq = c & 15;
            uint2 p; p.x = f2bf(xr[i].x, xr[i].y); p.y = f2bf(xr[i].z, xr[i].w);
            *(uint2*)(xb + tok * 72 + kq * 4) = p;
        }
#pragma unroll
        for (int i = 0; i < 5; ++i) {
            int c = t + i * 256;
            if (c < 1152) {
                int row = c >> 3, c8 = c & 7;
                *(uint4*)(ab + row * 72 + c8 * 8) = ar[i];
            }
        }
    };

    LD(0);
    WR(0);
    for (int s = 0; s < 16; ++s) {
        const int cur = s & 1;
        __syncthreads();                       // buf[cur] ready; prev reads drained
        if (s < 15) LD((s + 1) * 64);          // issue next loads (hidden under MFMA)
        const short* xb = xs + cur * (64 * 72);
        const short* ab = as_ + cur * (144 * 72);
#pragma unroll
        for (int ks = 0; ks < 2; ++ks) {
            bf16x8 af = *(const bf16x8*)(xb + (w * 16 + l15) * 72 + ks * 32 + lq * 8);
#pragma unroll
            for (int n = 0; n < 9; ++n) {
                bf16x8 bf = *(const bf16x8*)(ab + (n * 16 + l15) * 72 + ks * 32 + lq * 8);
                acc[n] = __builtin_amdgcn_mfma_f32_16x16x32_bf16(af, bf, acc[n], 0, 0, 0);
            }
        }
        if (s < 15) WR(cur ^ 1);
    }
    __syncthreads();

    // acc -> hsm[64][148]  (C/D layout: col=lane&15, row=(lane>>4)*4+reg)
#pragma unroll
    for (int n = 0; n < 9; ++n) {
#pragma unroll
        for (int r = 0; r < 4; ++r) {
            int row = w * 16 + lq * 4 + r;
            hsm[row * 148 + n * 16 + l15] = acc[n][r];
        }
    }
    __syncthreads();

    // softmax over experts, fold SCALE
    if (t < 64) {
        float m = -1e30f;
#pragma unroll
        for (int e = 0; e < NE; ++e) m = fmaxf(m, hsm[t * 148 + NF + e]);
        float p[NE], sum = 0.f;
#pragma unroll
        for (int e = 0; e < NE; ++e) { p[e] = expf(hsm[t * 148 + NF + e] - m); sum += p[e]; }
        float inv = SCALE / sum;
#pragma unroll
        for (int e = 0; e < NE; ++e) hsm[t * 148 + NF + e] = p[e] * inv;
    }
    __syncthreads();

    // weight by route, cvt to bf16, store wh[tok][128]
#pragma unroll
    for (int i = 0; i < 4; ++i) {
        int c = t + i * 256, tok = c >> 4, c8 = c & 15;
        const float* hr = hsm + tok * 148;
        float rt = hr[NF + (c8 >> 1)];
        float f0 = hr[c8 * 8 + 0] * rt, f1 = hr[c8 * 8 + 1] * rt;
        float f2 = hr[c8 * 8 + 2] * rt, f3 = hr[c8 * 8 + 3] * rt;
        float f4 = hr[c8 * 8 + 4] * rt, f5 = hr[c8 * 8 + 5] * rt;
        float f6 = hr[c8 * 8 + 6] * rt, f7 = hr[c8 * 8 + 7] * rt;
        uint4 pk; pk.x = f2bf(f0, f1); pk.y = f2bf(f2, f3);
        pk.z = f2bf(f4, f5); pk.w = f2bf(f6, f7);
        *(uint4*)(wh + (size_t)(tokb + tok) * NF + c8 * 8) = pk;
    }
}

// ---------------------------------------------------------------------------
// K2: per (otile, 64-tok tile): MFMA GEMM wh_g[64][64] x Bbt_g^T[64][128]
//     -> out cols; middle third zero-filled.
__global__ __launch_bounds__(256) void k2_up(const unsigned short* __restrict__ wh,
                                             const unsigned short* __restrict__ Bbt,
                                             float* __restrict__ out) {
    const int otile = blockIdx.x;          // 0..23
    const int tokb  = blockIdx.y * 64;
    const int t     = threadIdx.x;

    if (otile >= 8 && otile < 16) {        // disabled middle third -> zeros
        const int o0 = 1024 + (otile - 8) * 128;
        float4 z = {0.f, 0.f, 0.f, 0.f};
#pragma unroll
        for (int i = 0; i < 8; ++i) {
            int idx = t + i * 256, tok = idx >> 5, c4 = idx & 31;
            *(float4*)(out + (size_t)(tokb + tok) * NOUT + o0 + c4 * 4) = z;
        }
        return;
    }

    const int g    = (otile < 8) ? 0 : 1;
    const int o0   = (otile & 7) * 128;
    const int colb = (g ? 2048 : 0) + o0;

    __shared__ __align__(16) short whs[64 * 72];
    __shared__ __align__(16) short bws[128 * 72];

    // stage wh for this group: whs[tok][er], er = e*8+r  (gather f = e*16+g*8+r)
#pragma unroll
    for (int i = 0; i < 2; ++i) {
        int c = t + i * 256, tok = c >> 3, e = c & 7;
        uint4 v = *(const uint4*)(wh + (size_t)(tokb + tok) * NF + e * 16 + g * 8);
        *(uint4*)(whs + tok * 72 + e * 8) = v;
    }
    // stage Bbt tile: bws[o][er]
#pragma unroll
    for (int i = 0; i < 4; ++i) {
        int c = t + i * 256, row = c >> 3, c8 = c & 7;
        uint4 v = *(const uint4*)(Bbt + ((size_t)(g << 10) + o0 + row) * 64 + c8 * 8);
        *(uint4*)(bws + row * 72 + c8 * 8) = v;
    }
    __syncthreads();

    const int lane = t & 63, w = t >> 6;
    const int l15 = lane & 15, lq = lane >> 4;
    f32x4 acc[8];
#pragma unroll
    for (int n = 0; n < 8; ++n) acc[n] = (f32x4){0.f, 0.f, 0.f, 0.f};

#pragma unroll
    for (int ks = 0; ks < 2; ++ks) {
        bf16x8 af = *(const bf16x8*)(whs + (w * 16 + l15) * 72 + ks * 32 + lq * 8);
#pragma unroll
        for (int n = 0; n < 8; ++n) {
            bf16x8 bf = *(const bf16x8*)(bws + (n * 16 + l15) * 72 + ks * 32 + lq * 8);
            acc[n] = __builtin_amdgcn_mfma_f32_16x16x32_bf16(af, bf, acc[n], 0, 0, 0);
        }
    }

    // store (dword per lane; 16 lanes cover 64 contiguous bytes)
#pragma unroll
    for (int n = 0; n < 8; ++n) {
#pragma unroll
        for (int r = 0; r < 4; ++r) {
            int row = w * 16 + lq * 4 + r;
            out[(size_t)(tokb + row) * NOUT + colb + n * 16 + l15] = acc[n][r];
        }
    }
}

// ---------------------------------------------------------------------------
extern "C" void kernel_launch(void* const* d_in, const int* in_sizes, int n_in,
                              void* d_out, int out_size, void* d_ws, size_t ws_size,
                              hipStream_t stream) {
    const float* x  = (const float*)d_in[0];
    const float* Wr = (const float*)d_in[1];
    const float* A  = (const float*)d_in[2];
    const float* Bw = (const float*)d_in[3];
    unsigned short* Abt = (unsigned short*)((char*)d_ws + WS_ABT);
    unsigned short* Bbt = (unsigned short*)((char*)d_ws + WS_BBT);
    unsigned short* wh  = (unsigned short*)((char*)d_ws + WS_WH);
    float* out = (float*)d_out;

    k_prep<<<FP + 128, 256, 0, stream>>>(A, Wr, Bw, Abt, Bbt);
    k1_down<<<NTOK / 64, 256, 0, stream>>>(x, Abt, wh);
    k2_up<<<dim3(24, NTOK / 64), 256, 0, stream>>>(wh, Bbt, out);
}